// Round 1
// baseline (383.956 us; speedup 1.0000x reference)
//
#include <hip/hip_runtime.h>
#include <hip/hip_bf16.h>

#define TT 2048
#define DD 1024
#define HH 16
#define DHH 64
#define MM 4096  // B*T

typedef __attribute__((ext_vector_type(8))) short short8;
typedef __attribute__((ext_vector_type(4))) float floatx4;

__device__ __forceinline__ unsigned short f2bf(float f) {
    union { float f; unsigned int u; } v; v.f = f;
    return (unsigned short)((v.u + 0x7fffu + ((v.u >> 16) & 1u)) >> 16);  // RNE
}

__device__ __forceinline__ int swz(int row) { return (row & 3) ^ ((row >> 2) & 3); }

typedef __attribute__((address_space(1))) void gv_t;
typedef __attribute__((address_space(3))) void lv_t;
__device__ __forceinline__ void load_lds16(const void* g, void* l) {
    __builtin_amdgcn_global_load_lds((gv_t*)g, (lv_t*)l, 16, 0, 0);
}

// ---------------- cast fp32 -> bf16 (vectorized) ----------------
__global__ __launch_bounds__(256) void cast_bf16_k(const float* __restrict__ s,
                                                   unsigned short* __restrict__ d, int n4) {
    int i = blockIdx.x * 256 + threadIdx.x;
    if (i < n4) {
        float4 v = ((const float4*)s)[i];
        ushort4 o;
        o.x = f2bf(v.x); o.y = f2bf(v.y); o.z = f2bf(v.z); o.w = f2bf(v.w);
        ((ushort4*)d)[i] = o;
    }
}

// ---------------- xa = x @ [wq_A; wv_A]^T  -> [4096,16] fp32 ----------------
__global__ __launch_bounds__(256) void lora_xa_k(const float* __restrict__ x,
                                                 const float* __restrict__ qA,
                                                 const float* __restrict__ vA,
                                                 float* __restrict__ xa) {
    int wv = threadIdx.x >> 6, lane = threadIdx.x & 63;
    int m = blockIdx.x * 4 + wv;
    const float* xr = x + (size_t)m * DD;
    float acc[16];
#pragma unroll
    for (int j = 0; j < 16; ++j) acc[j] = 0.f;
    for (int k0 = 0; k0 < DD; k0 += 64) {
        float xvv = xr[k0 + lane];
#pragma unroll
        for (int j = 0; j < 8; ++j) {
            acc[j]     += xvv * qA[j * DD + k0 + lane];
            acc[8 + j] += xvv * vA[j * DD + k0 + lane];
        }
    }
#pragma unroll
    for (int j = 0; j < 16; ++j) {
        float a = acc[j];
#pragma unroll
        for (int off = 32; off >= 1; off >>= 1) a += __shfl_xor(a, off, 64);
        acc[j] = a;
    }
    if (lane == 0) {
#pragma unroll
        for (int j = 0; j < 16; ++j) xa[m * 16 + j] = acc[j];
    }
}

// ---------------- 128x128 NT GEMM, bf16 MFMA, global_load_lds staging ----------------
// MODE 0: C fp32 plain [M,N] (final O-proj). MODE 1: QKV, z-switch, lora epilogue, bf16 [b,h,t,dh] out.
template <int MODE>
__global__ __launch_bounds__(256) void gemm_nt_k(
        const unsigned short* __restrict__ A,
        const unsigned short* __restrict__ W0,
        const unsigned short* __restrict__ W1,
        const unsigned short* __restrict__ W2,
        unsigned short* __restrict__ Oq,
        unsigned short* __restrict__ Ok,
        unsigned short* __restrict__ Ov,
        float* __restrict__ Cf,
        const float* __restrict__ xa,
        const float* __restrict__ qB,
        const float* __restrict__ vB) {
    constexpr int K = DD;
    const int z = (MODE == 1) ? blockIdx.z : 0;
    const unsigned short* Bw = (MODE == 0) ? W0 : (z == 0 ? W0 : (z == 1 ? W1 : W2));
    const int tileM = blockIdx.y * 128, tileN = blockIdx.x * 128;
    __shared__ unsigned short lds[8192];  // A: [0,4096) elems, B: [4096,8192); row stride 32 elems
    const int tid = threadIdx.x, w = tid >> 6, lane = tid & 63;
    const int col = lane & 15, quad = lane >> 4;
    const int wm = (w >> 1) * 64, wn = (w & 1) * 64;

    floatx4 acc[4][4];
#pragma unroll
    for (int mi = 0; mi < 4; ++mi)
#pragma unroll
        for (int ni = 0; ni < 4; ++ni) acc[mi][ni] = (floatx4){0.f, 0.f, 0.f, 0.f};

    // staging: wave w owns 16-row slices {2w, 2w+1} of both A- and B-tiles.
    // LDS(row, c_lds) holds global k-chunk (c_lds ^ swz(row)); swz(row+16)==swz(row).
    const int sA = 2 * w;
    const int row0 = sA * 16 + (lane >> 2);
    const int cg = (lane & 3) ^ swz(row0);
    const unsigned short* gA0 = A  + (size_t)(tileM + row0) * K + cg * 8;
    const unsigned short* gB0 = Bw + (size_t)(tileN + row0) * K + cg * 8;

    for (int k0 = 0; k0 < K; k0 += 32) {
        __syncthreads();
        load_lds16(gA0 + k0,           lds + sA * 512);
        load_lds16(gA0 + 16 * K + k0,  lds + sA * 512 + 512);
        load_lds16(gB0 + k0,           lds + 4096 + sA * 512);
        load_lds16(gB0 + 16 * K + k0,  lds + 4096 + sA * 512 + 512);
        __syncthreads();
        short8 af[4], bf8[4];
#pragma unroll
        for (int mi = 0; mi < 4; ++mi) {
            int row = wm + mi * 16 + col;
            af[mi] = *(const short8*)(lds + row * 32 + ((quad ^ swz(row)) * 8));
        }
#pragma unroll
        for (int ni = 0; ni < 4; ++ni) {
            int row = wn + ni * 16 + col;
            bf8[ni] = *(const short8*)(lds + 4096 + row * 32 + ((quad ^ swz(row)) * 8));
        }
#pragma unroll
        for (int mi = 0; mi < 4; ++mi)
#pragma unroll
            for (int ni = 0; ni < 4; ++ni)
                acc[mi][ni] = __builtin_amdgcn_mfma_f32_16x16x32_bf16(af[mi], bf8[ni], acc[mi][ni], 0, 0, 0);
    }

    const bool lora = (MODE == 1) && (z != 1);
    const float scale = (MODE == 1 && z == 0) ? 0.125f : 1.0f;  // fold 1/sqrt(DH) into Q
    unsigned short* Ob = (MODE == 1) ? (z == 0 ? Oq : (z == 1 ? Ok : Ov)) : (unsigned short*)0;
    const float* lB = (z == 2) ? vB : qB;
    const int xoff = (z == 2) ? 8 : 0;

    float wb[4][8];
    if (lora) {
#pragma unroll
        for (int ni = 0; ni < 4; ++ni) {
            int n = tileN + wn + ni * 16 + col;
            const float4* p = (const float4*)(lB + n * 8);
            float4 w0v = p[0], w1v = p[1];
            wb[ni][0] = w0v.x; wb[ni][1] = w0v.y; wb[ni][2] = w0v.z; wb[ni][3] = w0v.w;
            wb[ni][4] = w1v.x; wb[ni][5] = w1v.y; wb[ni][6] = w1v.z; wb[ni][7] = w1v.w;
        }
    }
#pragma unroll
    for (int mi = 0; mi < 4; ++mi) {
#pragma unroll
        for (int r = 0; r < 4; ++r) {
            int m = tileM + wm + mi * 16 + quad * 4 + r;
            float xv[8];
            if (lora) {
                const float4* p = (const float4*)(xa + m * 16 + xoff);
                float4 x0 = p[0], x1 = p[1];
                xv[0] = x0.x; xv[1] = x0.y; xv[2] = x0.z; xv[3] = x0.w;
                xv[4] = x1.x; xv[5] = x1.y; xv[6] = x1.z; xv[7] = x1.w;
            }
#pragma unroll
            for (int ni = 0; ni < 4; ++ni) {
                int n = tileN + wn + ni * 16 + col;
                float val = acc[mi][ni][r];
                if (lora) {
                    float dlt = 0.f;
#pragma unroll
                    for (int j = 0; j < 8; ++j) dlt += xv[j] * wb[ni][j];
                    val += 2.f * dlt;  // SCALING = alpha/r = 2
                }
                val *= scale;
                if (MODE == 0) {
                    Cf[(size_t)m * DD + n] = val;
                } else {
                    int b = m >> 11, t = m & 2047, h = n >> 6, d2 = n & 63;
                    Ob[((size_t)(b * HH + h) * TT + t) * DHH + d2] = f2bf(val);
                }
            }
        }
    }
}

// ---------------- causal flash attention, 128-row Q tile per block ----------------
__global__ __launch_bounds__(256) void attn_k(const unsigned short* __restrict__ q,
                                              const unsigned short* __restrict__ k,
                                              const unsigned short* __restrict__ v,
                                              unsigned short* __restrict__ o) {
    __shared__ unsigned short Ps[128 * 136];  // P, padded rows (272B: 2-way bank alias only)
    __shared__ unsigned short Vs[64 * 136];   // V^T: [dh][kpos], same padding
    const int qt = blockIdx.x, bh = blockIdx.y;
    const int b = bh >> 4, h = bh & 15;
    const unsigned short* qp = q + (size_t)bh * TT * DHH;
    const unsigned short* kp = k + (size_t)bh * TT * DHH;
    const unsigned short* vp = v + (size_t)bh * TT * DHH;
    const int tid = threadIdx.x, w = tid >> 6, lane = tid & 63;
    const int col = lane & 15, quad = lane >> 4;

    // Q fragments in registers (Q pre-scaled by 1/8); wave w owns q-rows [w*32, w*32+32)
    short8 aq[2][2];
#pragma unroll
    for (int mt = 0; mt < 2; ++mt) {
        int t = qt * 128 + w * 32 + mt * 16 + col;
#pragma unroll
        for (int ks = 0; ks < 2; ++ks)
            aq[mt][ks] = *(const short8*)(qp + (size_t)t * DHH + ks * 32 + quad * 8);
    }
    float mrun[2][4], lrun[2][4];
    floatx4 oacc[2][4];
#pragma unroll
    for (int mt = 0; mt < 2; ++mt) {
#pragma unroll
        for (int r = 0; r < 4; ++r) { mrun[mt][r] = -1e30f; lrun[mt][r] = 0.f; }
#pragma unroll
        for (int nt = 0; nt < 4; ++nt) oacc[mt][nt] = (floatx4){0.f, 0.f, 0.f, 0.f};
    }

    for (int kt = 0; kt <= qt; ++kt) {
        // stage V transposed: Vs[dh][kpos]
        const unsigned short* vt = vp + (size_t)kt * 128 * DHH;
#pragma unroll
        for (int it = 0; it < 8; ++it) {
            int idx = it * 1024 + tid * 4;
            int r = idx >> 6, c = idx & 63;
            ushort4 vv = *(const ushort4*)(vt + r * 64 + c);
            Vs[(c + 0) * 136 + r] = vv.x;
            Vs[(c + 1) * 136 + r] = vv.y;
            Vs[(c + 2) * 136 + r] = vv.z;
            Vs[(c + 3) * 136 + r] = vv.w;
        }
        // S = Q K^T (K frags direct from global; L2-resident)
        floatx4 sacc[2][8];
#pragma unroll
        for (int nt = 0; nt < 8; ++nt) {
            int kr = kt * 128 + nt * 16 + col;
            short8 bk0 = *(const short8*)(kp + (size_t)kr * DHH + quad * 8);
            short8 bk1 = *(const short8*)(kp + (size_t)kr * DHH + 32 + quad * 8);
#pragma unroll
            for (int mt = 0; mt < 2; ++mt) {
                floatx4 t4 = (floatx4){0.f, 0.f, 0.f, 0.f};
                t4 = __builtin_amdgcn_mfma_f32_16x16x32_bf16(aq[mt][0], bk0, t4, 0, 0, 0);
                t4 = __builtin_amdgcn_mfma_f32_16x16x32_bf16(aq[mt][1], bk1, t4, 0, 0, 0);
                sacc[mt][nt] = t4;
            }
        }
        if (kt == qt) {  // diagonal tile: causal mask
#pragma unroll
            for (int mt = 0; mt < 2; ++mt)
#pragma unroll
                for (int nt = 0; nt < 8; ++nt)
#pragma unroll
                    for (int r = 0; r < 4; ++r) {
                        int qpos = w * 32 + mt * 16 + quad * 4 + r;
                        int kpos = nt * 16 + col;
                        if (kpos > qpos) sacc[mt][nt][r] = -1e30f;
                    }
        }
        // online softmax (state rows == C-layout rows: quad*4+r)
        float alpha[2][4];
#pragma unroll
        for (int mt = 0; mt < 2; ++mt)
#pragma unroll
            for (int r = 0; r < 4; ++r) {
                float mx = sacc[mt][0][r];
#pragma unroll
                for (int nt = 1; nt < 8; ++nt) mx = fmaxf(mx, sacc[mt][nt][r]);
                mx = fmaxf(mx, __shfl_xor(mx, 1, 64));
                mx = fmaxf(mx, __shfl_xor(mx, 2, 64));
                mx = fmaxf(mx, __shfl_xor(mx, 4, 64));
                mx = fmaxf(mx, __shfl_xor(mx, 8, 64));
                float mnew = fmaxf(mrun[mt][r], mx);
                alpha[mt][r] = __expf(mrun[mt][r] - mnew);
                mrun[mt][r] = mnew;
            }
        float rsum[2][4] = {};
#pragma unroll
        for (int mt = 0; mt < 2; ++mt)
#pragma unroll
            for (int nt = 0; nt < 8; ++nt)
#pragma unroll
                for (int r = 0; r < 4; ++r) {
                    float p = __expf(sacc[mt][nt][r] - mrun[mt][r]);
                    sacc[mt][nt][r] = p;
                    rsum[mt][r] += p;
                }
#pragma unroll
        for (int mt = 0; mt < 2; ++mt)
#pragma unroll
            for (int r = 0; r < 4; ++r) {
                float s = rsum[mt][r];
                s += __shfl_xor(s, 1, 64);
                s += __shfl_xor(s, 2, 64);
                s += __shfl_xor(s, 4, 64);
                s += __shfl_xor(s, 8, 64);
                lrun[mt][r] = lrun[mt][r] * alpha[mt][r] + s;
            }
#pragma unroll
        for (int mt = 0; mt < 2; ++mt)
#pragma unroll
            for (int nt = 0; nt < 4; ++nt)
#pragma unroll
                for (int r = 0; r < 4; ++r) oacc[mt][nt][r] *= alpha[mt][r];
        // P -> LDS (C-layout -> A-operand layout transform)
#pragma unroll
        for (int mt = 0; mt < 2; ++mt)
#pragma unroll
            for (int nt = 0; nt < 8; ++nt)
#pragma unroll
                for (int r = 0; r < 4; ++r)
                    Ps[(w * 32 + mt * 16 + quad * 4 + r) * 136 + nt * 16 + col] =
                        f2bf(sacc[mt][nt][r]);
        __syncthreads();
        // O += P V
#pragma unroll
        for (int ks = 0; ks < 4; ++ks) {
            short8 ap[2], bv[4];
#pragma unroll
            for (int mt = 0; mt < 2; ++mt)
                ap[mt] = *(const short8*)(Ps + (w * 32 + mt * 16 + col) * 136 + ks * 32 + quad * 8);
#pragma unroll
            for (int nt = 0; nt < 4; ++nt)
                bv[nt] = *(const short8*)(Vs + (nt * 16 + col) * 136 + ks * 32 + quad * 8);
#pragma unroll
            for (int mt = 0; mt < 2; ++mt)
#pragma unroll
                for (int nt = 0; nt < 4; ++nt)
                    oacc[mt][nt] = __builtin_amdgcn_mfma_f32_16x16x32_bf16(ap[mt], bv[nt], oacc[mt][nt], 0, 0, 0);
        }
        __syncthreads();
    }
    // epilogue: normalize, write [b, t, h*64+dh] bf16 for the O-projection GEMM
#pragma unroll
    for (int mt = 0; mt < 2; ++mt)
#pragma unroll
        for (int nt = 0; nt < 4; ++nt)
#pragma unroll
            for (int r = 0; r < 4; ++r) {
                int t = qt * 128 + w * 32 + mt * 16 + quad * 4 + r;
                int d2 = nt * 16 + col;
                float val = oacc[mt][nt][r] / lrun[mt][r];
                o[((size_t)(b * TT + t)) * DD + h * DHH + d2] = f2bf(val);
            }
}

extern "C" void kernel_launch(void* const* d_in, const int* in_sizes, int n_in,
                              void* d_out, int out_size, void* d_ws, size_t ws_size,
                              hipStream_t stream) {
    const float* x    = (const float*)d_in[0];
    // d_in[1] = attn_mask (causal, known analytically — unused)
    const float* wq_w = (const float*)d_in[2];
    const float* wq_A = (const float*)d_in[3];
    const float* wq_B = (const float*)d_in[4];
    const float* wk_w = (const float*)d_in[5];
    const float* wv_w = (const float*)d_in[6];
    const float* wv_A = (const float*)d_in[7];
    const float* wv_B = (const float*)d_in[8];
    const float* wo_w = (const float*)d_in[9];
    float* out = (float*)d_out;

    char* ws = (char*)d_ws;
    unsigned short* xb  = (unsigned short*)(ws + 0);         // 8 MB
    unsigned short* wqb = (unsigned short*)(ws + 8388608);   // 2 MB
    unsigned short* wkb = (unsigned short*)(ws + 10485760);
    unsigned short* wvb = (unsigned short*)(ws + 12582912);
    unsigned short* wob = (unsigned short*)(ws + 14680064);
    float*          xa  = (float*)         (ws + 16777216);  // 256 KB
    unsigned short* qb  = (unsigned short*)(ws + 17039360);  // 8 MB each, [b,h,t,dh]
    unsigned short* kb  = (unsigned short*)(ws + 25427968);
    unsigned short* vb  = (unsigned short*)(ws + 33816576);
    unsigned short* ob  = (unsigned short*)(ws + 42205184);  // 8 MB, [b,t,h*dh]

    cast_bf16_k<<<4096, 256, 0, stream>>>(x, xb, 1048576);
    cast_bf16_k<<<1024, 256, 0, stream>>>(wq_w, wqb, 262144);
    cast_bf16_k<<<1024, 256, 0, stream>>>(wk_w, wkb, 262144);
    cast_bf16_k<<<1024, 256, 0, stream>>>(wv_w, wvb, 262144);
    cast_bf16_k<<<1024, 256, 0, stream>>>(wo_w, wob, 262144);
    lora_xa_k<<<1024, 256, 0, stream>>>(x, wq_A, wv_A, xa);
    gemm_nt_k<1><<<dim3(8, 32, 3), 256, 0, stream>>>(xb, wqb, wkb, wvb, qb, kb, vb,
                                                     nullptr, xa, wq_B, wv_B);
    attn_k<<<dim3(16, 32), 256, 0, stream>>>(qb, kb, vb, ob);
    gemm_nt_k<0><<<dim3(8, 32, 1), 256, 0, stream>>>(ob, wob, nullptr, nullptr,
                                                     nullptr, nullptr, nullptr, out,
                                                     nullptr, nullptr, nullptr);
}

// Round 2
// 297.587 us; speedup vs baseline: 1.2902x; 1.2902x over previous
//
#include <hip/hip_runtime.h>
#include <hip/hip_bf16.h>

#define TT 2048
#define DD 1024
#define HH 16
#define DHH 64
#define MM 4096  // B*T

typedef __attribute__((ext_vector_type(8))) short short8;
typedef __attribute__((ext_vector_type(4))) float floatx4;

__device__ __forceinline__ unsigned short f2bf(float f) {
    union { float f; unsigned int u; } v; v.f = f;
    return (unsigned short)((v.u + 0x7fffu + ((v.u >> 16) & 1u)) >> 16);  // RNE
}
__device__ __forceinline__ float bf2f(unsigned short u) {
    union { unsigned int i; float f; } v; v.i = ((unsigned int)u) << 16; return v.f;
}

__device__ __forceinline__ int swz(int row) { return (row & 3) ^ ((row >> 2) & 3); }

typedef __attribute__((address_space(1))) void gv_t;
typedef __attribute__((address_space(3))) void lv_t;
__device__ __forceinline__ void load_lds16(const void* g, void* l) {
    __builtin_amdgcn_global_load_lds((gv_t*)g, (lv_t*)l, 16, 0, 0);
}

// DPP row-rotate (within 16-lane rows) — VALU-speed cross-lane reduce
template <int CTRL>
__device__ __forceinline__ float dpp_rot(float v) {
    int x = __builtin_amdgcn_update_dpp(0, __float_as_int(v), CTRL, 0xf, 0xf, true);
    return __int_as_float(x);
}
__device__ __forceinline__ float rowmax16(float v) {
    v = fmaxf(v, dpp_rot<0x121>(v));  // ror:1
    v = fmaxf(v, dpp_rot<0x122>(v));  // ror:2
    v = fmaxf(v, dpp_rot<0x124>(v));  // ror:4
    v = fmaxf(v, dpp_rot<0x128>(v));  // ror:8
    return v;
}

// ---------------- fused cast fp32 -> bf16 for x + 4 weights (1 launch) ----------------
__global__ __launch_bounds__(256) void cast_all_k(
        const float* __restrict__ x, const float* __restrict__ w0,
        const float* __restrict__ w1, const float* __restrict__ w2,
        const float* __restrict__ w3,
        unsigned short* __restrict__ xb, unsigned short* __restrict__ d0,
        unsigned short* __restrict__ d1, unsigned short* __restrict__ d2,
        unsigned short* __restrict__ d3) {
    int bid = blockIdx.x;
    const float* s; unsigned short* d; int i;
    if (bid < 4096) { s = x; d = xb; i = bid * 256 + threadIdx.x; }
    else {
        int seg = (bid - 4096) >> 10;
        i = ((bid - 4096) & 1023) * 256 + threadIdx.x;
        s = (seg == 0) ? w0 : (seg == 1) ? w1 : (seg == 2) ? w2 : w3;
        d = (seg == 0) ? d0 : (seg == 1) ? d1 : (seg == 2) ? d2 : d3;
    }
    float4 v = ((const float4*)s)[i];
    ushort4 o;
    o.x = f2bf(v.x); o.y = f2bf(v.y); o.z = f2bf(v.z); o.w = f2bf(v.w);
    ((ushort4*)d)[i] = o;
}

// ---------------- xa = x @ [wq_A; wv_A]^T  -> [4096,16] fp32 ----------------
__global__ __launch_bounds__(256) void lora_xa_k(const float* __restrict__ x,
                                                 const float* __restrict__ qA,
                                                 const float* __restrict__ vA,
                                                 float* __restrict__ xa) {
    int wv = threadIdx.x >> 6, lane = threadIdx.x & 63;
    int m = blockIdx.x * 4 + wv;
    const float* xr = x + (size_t)m * DD;
    float acc[16];
#pragma unroll
    for (int j = 0; j < 16; ++j) acc[j] = 0.f;
    for (int k0 = 0; k0 < DD; k0 += 64) {
        float xvv = xr[k0 + lane];
#pragma unroll
        for (int j = 0; j < 8; ++j) {
            acc[j]     += xvv * qA[j * DD + k0 + lane];
            acc[8 + j] += xvv * vA[j * DD + k0 + lane];
        }
    }
#pragma unroll
    for (int j = 0; j < 16; ++j) {
        float a = acc[j];
#pragma unroll
        for (int off = 32; off >= 1; off >>= 1) a += __shfl_xor(a, off, 64);
        acc[j] = a;
    }
    if (lane == 0) {
#pragma unroll
        for (int j = 0; j < 16; ++j) xa[m * 16 + j] = acc[j];
    }
}

// ---------------- 128x128 NT GEMM, bf16 MFMA, global_load_lds staging ----------------
template <int MODE>
__global__ __launch_bounds__(256) void gemm_nt_k(
        const unsigned short* __restrict__ A,
        const unsigned short* __restrict__ W0,
        const unsigned short* __restrict__ W1,
        const unsigned short* __restrict__ W2,
        unsigned short* __restrict__ Oq,
        unsigned short* __restrict__ Ok,
        unsigned short* __restrict__ Ov,
        float* __restrict__ Cf,
        const float* __restrict__ xa,
        const float* __restrict__ qB,
        const float* __restrict__ vB) {
    constexpr int K = DD;
    const int z = (MODE == 1) ? blockIdx.z : 0;
    const unsigned short* Bw = (MODE == 0) ? W0 : (z == 0 ? W0 : (z == 1 ? W1 : W2));
    const int tileM = blockIdx.y * 128, tileN = blockIdx.x * 128;
    __shared__ unsigned short lds[8192];
    const int tid = threadIdx.x, w = tid >> 6, lane = tid & 63;
    const int col = lane & 15, quad = lane >> 4;
    const int wm = (w >> 1) * 64, wn = (w & 1) * 64;

    floatx4 acc[4][4];
#pragma unroll
    for (int mi = 0; mi < 4; ++mi)
#pragma unroll
        for (int ni = 0; ni < 4; ++ni) acc[mi][ni] = (floatx4){0.f, 0.f, 0.f, 0.f};

    const int sA = 2 * w;
    const int row0 = sA * 16 + (lane >> 2);
    const int cg = (lane & 3) ^ swz(row0);
    const unsigned short* gA0 = A  + (size_t)(tileM + row0) * K + cg * 8;
    const unsigned short* gB0 = Bw + (size_t)(tileN + row0) * K + cg * 8;

    for (int k0 = 0; k0 < K; k0 += 32) {
        __syncthreads();
        load_lds16(gA0 + k0,           lds + sA * 512);
        load_lds16(gA0 + 16 * K + k0,  lds + sA * 512 + 512);
        load_lds16(gB0 + k0,           lds + 4096 + sA * 512);
        load_lds16(gB0 + 16 * K + k0,  lds + 4096 + sA * 512 + 512);
        __syncthreads();
        short8 af[4], bf8[4];
#pragma unroll
        for (int mi = 0; mi < 4; ++mi) {
            int row = wm + mi * 16 + col;
            af[mi] = *(const short8*)(lds + row * 32 + ((quad ^ swz(row)) * 8));
        }
#pragma unroll
        for (int ni = 0; ni < 4; ++ni) {
            int row = wn + ni * 16 + col;
            bf8[ni] = *(const short8*)(lds + 4096 + row * 32 + ((quad ^ swz(row)) * 8));
        }
#pragma unroll
        for (int mi = 0; mi < 4; ++mi)
#pragma unroll
            for (int ni = 0; ni < 4; ++ni)
                acc[mi][ni] = __builtin_amdgcn_mfma_f32_16x16x32_bf16(af[mi], bf8[ni], acc[mi][ni], 0, 0, 0);
    }

    const bool lora = (MODE == 1) && (z != 1);
    const float scale = (MODE == 1 && z == 0) ? 0.125f : 1.0f;
    unsigned short* Ob = (MODE == 1) ? (z == 0 ? Oq : (z == 1 ? Ok : Ov)) : (unsigned short*)0;
    const float* lB = (z == 2) ? vB : qB;
    const int xoff = (z == 2) ? 8 : 0;

    float wb[4][8];
    if (lora) {
#pragma unroll
        for (int ni = 0; ni < 4; ++ni) {
            int n = tileN + wn + ni * 16 + col;
            const float4* p = (const float4*)(lB + n * 8);
            float4 w0v = p[0], w1v = p[1];
            wb[ni][0] = w0v.x; wb[ni][1] = w0v.y; wb[ni][2] = w0v.z; wb[ni][3] = w0v.w;
            wb[ni][4] = w1v.x; wb[ni][5] = w1v.y; wb[ni][6] = w1v.z; wb[ni][7] = w1v.w;
        }
    }
#pragma unroll
    for (int mi = 0; mi < 4; ++mi) {
#pragma unroll
        for (int r = 0; r < 4; ++r) {
            int m = tileM + wm + mi * 16 + quad * 4 + r;
            float xv[8];
            if (lora) {
                const float4* p = (const float4*)(xa + m * 16 + xoff);
                float4 x0 = p[0], x1 = p[1];
                xv[0] = x0.x; xv[1] = x0.y; xv[2] = x0.z; xv[3] = x0.w;
                xv[4] = x1.x; xv[5] = x1.y; xv[6] = x1.z; xv[7] = x1.w;
            }
#pragma unroll
            for (int ni = 0; ni < 4; ++ni) {
                int n = tileN + wn + ni * 16 + col;
                float val = acc[mi][ni][r];
                if (lora) {
                    float dlt = 0.f;
#pragma unroll
                    for (int j = 0; j < 8; ++j) dlt += xv[j] * wb[ni][j];
                    val += 2.f * dlt;
                }
                val *= scale;
                if (MODE == 0) {
                    Cf[(size_t)m * DD + n] = val;
                } else {
                    int b = m >> 11, t = m & 2047, h = n >> 6, d2 = n & 63;
                    Ob[((size_t)(b * HH + h) * TT + t) * DHH + d2] = f2bf(val);
                }
            }
        }
    }
}

// ---------------- split-K causal flash attention: partial kernel ----------------
// grid.x = 24 (linearized (qt, chunk) pairs, chunk = 8 k-tiles), grid.y = bh
__global__ __launch_bounds__(256) void attn_part_k(
        const unsigned short* __restrict__ q,
        const unsigned short* __restrict__ k,
        const unsigned short* __restrict__ v,
        unsigned short* __restrict__ Op,
        float* __restrict__ Mp, float* __restrict__ Lp) {
    __shared__ unsigned short Ps[128 * 136];
    __shared__ unsigned short Vs[64 * 136];
    // decode (qt, chunk) from linear blockIdx.x; chunks per qt = (qt>>3)+1
    int rem = blockIdx.x, qt = 0;
    while (rem >= (qt >> 3) + 1) { rem -= (qt >> 3) + 1; ++qt; }
    const int ch = rem;
    const int bh = blockIdx.y;
    const int slot = bh * 24 + blockIdx.x;  // linear partial slot
    const unsigned short* qp = q + (size_t)bh * TT * DHH;
    const unsigned short* kp = k + (size_t)bh * TT * DHH;
    const unsigned short* vp = v + (size_t)bh * TT * DHH;
    const int tid = threadIdx.x, w = tid >> 6, lane = tid & 63;
    const int col = lane & 15, quad = lane >> 4;

    short8 aq[2][2];
#pragma unroll
    for (int mt = 0; mt < 2; ++mt) {
        int t = qt * 128 + w * 32 + mt * 16 + col;
#pragma unroll
        for (int ks = 0; ks < 2; ++ks)
            aq[mt][ks] = *(const short8*)(qp + (size_t)t * DHH + ks * 32 + quad * 8);
    }
    // ones B-fragment: column n=0 of a virtual V-extension -> row-sums of P
    unsigned short onev = (col == 0) ? (unsigned short)0x3F80 : (unsigned short)0;
    short8 bones;
#pragma unroll
    for (int j = 0; j < 8; ++j) bones[j] = (short)onev;

    float mrun[2][4];
    floatx4 oacc[2][4], oaccL[2];
#pragma unroll
    for (int mt = 0; mt < 2; ++mt) {
#pragma unroll
        for (int r = 0; r < 4; ++r) mrun[mt][r] = -1e30f;
#pragma unroll
        for (int nt = 0; nt < 4; ++nt) oacc[mt][nt] = (floatx4){0.f, 0.f, 0.f, 0.f};
        oaccL[mt] = (floatx4){0.f, 0.f, 0.f, 0.f};
    }

    const int kt0 = ch * 8;
    const int kt1 = (kt0 + 7 < qt) ? (kt0 + 7) : qt;
    // V staging assignment: thread owns kpos rows r0..r0+3, dh cols c0..c0+7
    const int r0 = (tid & 31) * 4, c0 = (tid >> 5) * 8;

    for (int kt = kt0; kt <= kt1; ++kt) {
        // stage V^T (register 4x8 transpose, b64 stores)
        const unsigned short* vt = vp + (size_t)kt * 128 * DHH;
        short8 rw0 = *(const short8*)(vt + (r0 + 0) * 64 + c0);
        short8 rw1 = *(const short8*)(vt + (r0 + 1) * 64 + c0);
        short8 rw2 = *(const short8*)(vt + (r0 + 2) * 64 + c0);
        short8 rw3 = *(const short8*)(vt + (r0 + 3) * 64 + c0);
#pragma unroll
        for (int j = 0; j < 8; ++j) {
            ushort4 o;
            o.x = (unsigned short)rw0[j]; o.y = (unsigned short)rw1[j];
            o.z = (unsigned short)rw2[j]; o.w = (unsigned short)rw3[j];
            *(ushort4*)(Vs + (c0 + j) * 136 + r0) = o;
        }
        // S = Q K^T
        floatx4 sacc[2][8];
#pragma unroll
        for (int nt = 0; nt < 8; ++nt) {
            int kr = kt * 128 + nt * 16 + col;
            short8 bk0 = *(const short8*)(kp + (size_t)kr * DHH + quad * 8);
            short8 bk1 = *(const short8*)(kp + (size_t)kr * DHH + 32 + quad * 8);
#pragma unroll
            for (int mt = 0; mt < 2; ++mt) {
                floatx4 t4 = (floatx4){0.f, 0.f, 0.f, 0.f};
                t4 = __builtin_amdgcn_mfma_f32_16x16x32_bf16(aq[mt][0], bk0, t4, 0, 0, 0);
                t4 = __builtin_amdgcn_mfma_f32_16x16x32_bf16(aq[mt][1], bk1, t4, 0, 0, 0);
                sacc[mt][nt] = t4;
            }
        }
        if (kt == qt) {  // diagonal tile: causal mask
#pragma unroll
            for (int mt = 0; mt < 2; ++mt)
#pragma unroll
                for (int nt = 0; nt < 8; ++nt)
#pragma unroll
                    for (int r = 0; r < 4; ++r) {
                        int qpos = w * 32 + mt * 16 + quad * 4 + r;
                        int kpos = nt * 16 + col;
                        if (kpos > qpos) sacc[mt][nt][r] = -1e30f;
                    }
        }
        // online softmax: DPP max, no sum shuffles (sum via ones-column MFMA)
        float alpha[2][4];
#pragma unroll
        for (int mt = 0; mt < 2; ++mt)
#pragma unroll
            for (int r = 0; r < 4; ++r) {
                float mx = sacc[mt][0][r];
#pragma unroll
                for (int nt = 1; nt < 8; ++nt) mx = fmaxf(mx, sacc[mt][nt][r]);
                mx = rowmax16(mx);
                float mnew = fmaxf(mrun[mt][r], mx);
                alpha[mt][r] = __expf(mrun[mt][r] - mnew);
                mrun[mt][r] = mnew;
            }
#pragma unroll
        for (int mt = 0; mt < 2; ++mt)
#pragma unroll
            for (int nt = 0; nt < 8; ++nt)
#pragma unroll
                for (int r = 0; r < 4; ++r) {
                    float p = __expf(sacc[mt][nt][r] - mrun[mt][r]);
                    Ps[(w * 32 + mt * 16 + quad * 4 + r) * 136 + nt * 16 + col] = f2bf(p);
                }
#pragma unroll
        for (int mt = 0; mt < 2; ++mt) {
#pragma unroll
            for (int nt = 0; nt < 4; ++nt)
#pragma unroll
                for (int r = 0; r < 4; ++r) oacc[mt][nt][r] *= alpha[mt][r];
#pragma unroll
            for (int r = 0; r < 4; ++r) oaccL[mt][r] *= alpha[mt][r];
        }
        __syncthreads();
        // O += P V ; L += P 1
#pragma unroll
        for (int ks = 0; ks < 4; ++ks) {
            short8 ap[2], bv[4];
#pragma unroll
            for (int mt = 0; mt < 2; ++mt)
                ap[mt] = *(const short8*)(Ps + (w * 32 + mt * 16 + col) * 136 + ks * 32 + quad * 8);
#pragma unroll
            for (int nt = 0; nt < 4; ++nt)
                bv[nt] = *(const short8*)(Vs + (nt * 16 + col) * 136 + ks * 32 + quad * 8);
#pragma unroll
            for (int mt = 0; mt < 2; ++mt) {
#pragma unroll
                for (int nt = 0; nt < 4; ++nt)
                    oacc[mt][nt] = __builtin_amdgcn_mfma_f32_16x16x32_bf16(ap[mt], bv[nt], oacc[mt][nt], 0, 0, 0);
                oaccL[mt] = __builtin_amdgcn_mfma_f32_16x16x32_bf16(ap[mt], bones, oaccL[mt], 0, 0, 0);
            }
        }
        __syncthreads();
    }
    // write partials: O unnormalized (bf16), m and l (col-0 lanes own l)
    unsigned short* ob = Op + (size_t)slot * 128 * 64;
#pragma unroll
    for (int mt = 0; mt < 2; ++mt)
#pragma unroll
        for (int nt = 0; nt < 4; ++nt)
#pragma unroll
            for (int r = 0; r < 4; ++r) {
                int row = w * 32 + mt * 16 + quad * 4 + r;
                ob[row * 64 + nt * 16 + col] = f2bf(oacc[mt][nt][r]);
            }
    if (col == 0) {
#pragma unroll
        for (int mt = 0; mt < 2; ++mt)
#pragma unroll
            for (int r = 0; r < 4; ++r) {
                int row = w * 32 + mt * 16 + quad * 4 + r;
                Mp[slot * 128 + row] = mrun[mt][r];
                Lp[slot * 128 + row] = oaccL[mt][r];
            }
    }
}

// ---------------- split-K combine: O = sum_c w_c O_c / sum_c w_c l_c ----------------
__global__ __launch_bounds__(256) void attn_comb_k(
        const unsigned short* __restrict__ Op, const float* __restrict__ Mp,
        const float* __restrict__ Lp, unsigned short* __restrict__ o) {
    const int qt = blockIdx.x, bh = blockIdx.y;
    const int g = qt >> 3, nc = g + 1;
    const int slot0 = bh * 24 + 4 * g * (g + 1) + (qt & 7) * (g + 1);
    const int b = bh >> 4, h = bh & 15;
    const int tid = threadIdx.x;
    const int row = tid >> 1, d0 = (tid & 1) * 32;
    float m0 = Mp[slot0 * 128 + row];
    float m1 = (nc > 1) ? Mp[(slot0 + 1) * 128 + row] : -1e30f;
    float M = fmaxf(m0, m1);
    float w0 = __expf(m0 - M);
    float w1 = (nc > 1) ? __expf(m1 - M) : 0.f;
    float ltot = w0 * Lp[slot0 * 128 + row];
    if (nc > 1) ltot += w1 * Lp[(slot0 + 1) * 128 + row];
    float inv = 1.0f / ltot;
    const unsigned short* p0 = Op + (size_t)slot0 * 8192 + row * 64 + d0;
    float acc[32];
#pragma unroll
    for (int c4 = 0; c4 < 4; ++c4) {
        short8 vv = *(const short8*)(p0 + c4 * 8);
#pragma unroll
        for (int j = 0; j < 8; ++j) acc[c4 * 8 + j] = w0 * bf2f((unsigned short)vv[j]);
    }
    if (nc > 1) {
        const unsigned short* p1 = p0 + 8192;
#pragma unroll
        for (int c4 = 0; c4 < 4; ++c4) {
            short8 vv = *(const short8*)(p1 + c4 * 8);
#pragma unroll
            for (int j = 0; j < 8; ++j) acc[c4 * 8 + j] += w1 * bf2f((unsigned short)vv[j]);
        }
    }
    unsigned short* po = o + ((size_t)(b * TT + qt * 128 + row)) * DD + h * DHH + d0;
#pragma unroll
    for (int c4 = 0; c4 < 4; ++c4) {
        short8 ov;
#pragma unroll
        for (int j = 0; j < 8; ++j) ov[j] = (short)f2bf(acc[c4 * 8 + j] * inv);
        *(short8*)(po + c4 * 8) = ov;
    }
}

extern "C" void kernel_launch(void* const* d_in, const int* in_sizes, int n_in,
                              void* d_out, int out_size, void* d_ws, size_t ws_size,
                              hipStream_t stream) {
    const float* x    = (const float*)d_in[0];
    const float* wq_w = (const float*)d_in[2];
    const float* wq_A = (const float*)d_in[3];
    const float* wq_B = (const float*)d_in[4];
    const float* wk_w = (const float*)d_in[5];
    const float* wv_w = (const float*)d_in[6];
    const float* wv_A = (const float*)d_in[7];
    const float* wv_B = (const float*)d_in[8];
    const float* wo_w = (const float*)d_in[9];
    float* out = (float*)d_out;

    char* ws = (char*)d_ws;
    unsigned short* xb  = (unsigned short*)(ws + 0);         // 8 MB   [dead after QKV gemm]
    unsigned short* wqb = (unsigned short*)(ws + 8388608);   // 2 MB   [dead after QKV gemm]
    unsigned short* wkb = (unsigned short*)(ws + 10485760);  //        [dead after QKV gemm]
    unsigned short* wvb = (unsigned short*)(ws + 12582912);  //        [dead after QKV gemm]
    unsigned short* wob = (unsigned short*)(ws + 14680064);  // 2 MB   [live until final gemm]
    float*          xa  = (float*)         (ws + 16777216);  // 256 KB
    unsigned short* qb  = (unsigned short*)(ws + 17039360);  // 8 MB each, [b,h,t,dh]
    unsigned short* kb  = (unsigned short*)(ws + 25427968);
    unsigned short* vb  = (unsigned short*)(ws + 33816576);
    unsigned short* ob  = (unsigned short*)(ws + 42205184);  // 8 MB, [b,t,h*dh]
    // split-K partials overlay the dead xb/wqb/wkb/wvb region (stream-ordered safe):
    unsigned short* Opart = (unsigned short*)(ws + 0);         // 32*24*8192*2 = 12,582,912 B
    float*          Mpart = (float*)         (ws + 12582912);  // 393,216 B
    float*          Lpart = (float*)         (ws + 12976128);  // 393,216 B  (ends < wob)

    cast_all_k<<<8192, 256, 0, stream>>>(x, wq_w, wk_w, wv_w, wo_w, xb, wqb, wkb, wvb, wob);
    lora_xa_k<<<1024, 256, 0, stream>>>(x, wq_A, wv_A, xa);
    gemm_nt_k<1><<<dim3(8, 32, 3), 256, 0, stream>>>(xb, wqb, wkb, wvb, qb, kb, vb,
                                                     nullptr, xa, wq_B, wv_B);
    attn_part_k<<<dim3(24, 32), 256, 0, stream>>>(qb, kb, vb, Opart, Mpart, Lpart);
    attn_comb_k<<<dim3(16, 32), 256, 0, stream>>>(Opart, Mpart, Lpart, ob);
    gemm_nt_k<0><<<dim3(8, 32, 1), 256, 0, stream>>>(ob, wob, nullptr, nullptr,
                                                     nullptr, nullptr, nullptr, out,
                                                     nullptr, nullptr, nullptr);
}

// Round 3
// 281.348 us; speedup vs baseline: 1.3647x; 1.0577x over previous
//
#include <hip/hip_runtime.h>
#include <hip/hip_bf16.h>

#define TT 2048
#define DD 1024
#define HH 16
#define DHH 64
#define MM 4096  // B*T

typedef __attribute__((ext_vector_type(8))) short short8;
typedef __attribute__((ext_vector_type(4))) float floatx4;

__device__ __forceinline__ unsigned short f2bf(float f) {
    union { float f; unsigned int u; } v; v.f = f;
    return (unsigned short)((v.u + 0x7fffu + ((v.u >> 16) & 1u)) >> 16);  // RNE
}
__device__ __forceinline__ float bf2f(unsigned short u) {
    union { unsigned int i; float f; } v; v.i = ((unsigned int)u) << 16; return v.f;
}
// pack two floats to packed bf16 pair (round-half-up) in 3 VALU ops
__device__ __forceinline__ unsigned int pack_bf16(float lo, float hi) {
    unsigned int a = __float_as_uint(lo) + 0x8000u;
    unsigned int b = __float_as_uint(hi) + 0x8000u;
    return __builtin_amdgcn_perm(b, a, 0x07060302u);  // {b.hi16, a.hi16}
}

__device__ __forceinline__ int swz(int row) { return (row & 3) ^ ((row >> 2) & 3); }

typedef __attribute__((address_space(1))) void gv_t;
typedef __attribute__((address_space(3))) void lv_t;
__device__ __forceinline__ void load_lds16(const void* g, void* l) {
    __builtin_amdgcn_global_load_lds((gv_t*)g, (lv_t*)l, 16, 0, 0);
}

// DPP row-rotate (within 16-lane rows) — VALU-speed cross-lane reduce
template <int CTRL>
__device__ __forceinline__ float dpp_rot(float v) {
    int x = __builtin_amdgcn_update_dpp(0, __float_as_int(v), CTRL, 0xf, 0xf, true);
    return __int_as_float(x);
}
__device__ __forceinline__ float rowmax16(float v) {
    v = fmaxf(v, dpp_rot<0x121>(v));  // ror:1
    v = fmaxf(v, dpp_rot<0x122>(v));  // ror:2
    v = fmaxf(v, dpp_rot<0x124>(v));  // ror:4
    v = fmaxf(v, dpp_rot<0x128>(v));  // ror:8
    return v;
}

// ---------------- fused cast fp32 -> bf16 for x + 4 weights (1 launch) ----------------
__global__ __launch_bounds__(256) void cast_all_k(
        const float* __restrict__ x, const float* __restrict__ w0,
        const float* __restrict__ w1, const float* __restrict__ w2,
        const float* __restrict__ w3,
        unsigned short* __restrict__ xb, unsigned short* __restrict__ d0,
        unsigned short* __restrict__ d1, unsigned short* __restrict__ d2,
        unsigned short* __restrict__ d3) {
    int bid = blockIdx.x;
    const float* s; unsigned short* d; int i;
    if (bid < 4096) { s = x; d = xb; i = bid * 256 + threadIdx.x; }
    else {
        int seg = (bid - 4096) >> 10;
        i = ((bid - 4096) & 1023) * 256 + threadIdx.x;
        s = (seg == 0) ? w0 : (seg == 1) ? w1 : (seg == 2) ? w2 : w3;
        d = (seg == 0) ? d0 : (seg == 1) ? d1 : (seg == 2) ? d2 : d3;
    }
    float4 v = ((const float4*)s)[i];
    ushort4 o;
    o.x = f2bf(v.x); o.y = f2bf(v.y); o.z = f2bf(v.z); o.w = f2bf(v.w);
    ((ushort4*)d)[i] = o;
}

// ---------------- xa = x @ [wq_A; wv_A]^T  -> [4096,16] fp32 ----------------
__global__ __launch_bounds__(256) void lora_xa_k(const float* __restrict__ x,
                                                 const float* __restrict__ qA,
                                                 const float* __restrict__ vA,
                                                 float* __restrict__ xa) {
    int wv = threadIdx.x >> 6, lane = threadIdx.x & 63;
    int m = blockIdx.x * 4 + wv;
    const float* xr = x + (size_t)m * DD;
    float acc[16];
#pragma unroll
    for (int j = 0; j < 16; ++j) acc[j] = 0.f;
    for (int k0 = 0; k0 < DD; k0 += 64) {
        float xvv = xr[k0 + lane];
#pragma unroll
        for (int j = 0; j < 8; ++j) {
            acc[j]     += xvv * qA[j * DD + k0 + lane];
            acc[8 + j] += xvv * vA[j * DD + k0 + lane];
        }
    }
#pragma unroll
    for (int j = 0; j < 16; ++j) {
        float a = acc[j];
#pragma unroll
        for (int off = 32; off >= 1; off >>= 1) a += __shfl_xor(a, off, 64);
        acc[j] = a;
    }
    if (lane == 0) {
#pragma unroll
        for (int j = 0; j < 16; ++j) xa[m * 16 + j] = acc[j];
    }
}

// ---------------- 128x128 NT GEMM, bf16 MFMA, global_load_lds staging ----------------
template <int MODE>
__global__ __launch_bounds__(256) void gemm_nt_k(
        const unsigned short* __restrict__ A,
        const unsigned short* __restrict__ W0,
        const unsigned short* __restrict__ W1,
        const unsigned short* __restrict__ W2,
        unsigned short* __restrict__ Oq,
        unsigned short* __restrict__ Ok,
        unsigned short* __restrict__ Ov,
        float* __restrict__ Cf,
        const float* __restrict__ xa,
        const float* __restrict__ qB,
        const float* __restrict__ vB) {
    constexpr int K = DD;
    const int z = (MODE == 1) ? blockIdx.z : 0;
    const unsigned short* Bw = (MODE == 0) ? W0 : (z == 0 ? W0 : (z == 1 ? W1 : W2));
    const int tileM = blockIdx.y * 128, tileN = blockIdx.x * 128;
    __shared__ unsigned short lds[8192];
    const int tid = threadIdx.x, w = tid >> 6, lane = tid & 63;
    const int col = lane & 15, quad = lane >> 4;
    const int wm = (w >> 1) * 64, wn = (w & 1) * 64;

    floatx4 acc[4][4];
#pragma unroll
    for (int mi = 0; mi < 4; ++mi)
#pragma unroll
        for (int ni = 0; ni < 4; ++ni) acc[mi][ni] = (floatx4){0.f, 0.f, 0.f, 0.f};

    const int sA = 2 * w;
    const int row0 = sA * 16 + (lane >> 2);
    const int cg = (lane & 3) ^ swz(row0);
    const unsigned short* gA0 = A  + (size_t)(tileM + row0) * K + cg * 8;
    const unsigned short* gB0 = Bw + (size_t)(tileN + row0) * K + cg * 8;

    for (int k0 = 0; k0 < K; k0 += 32) {
        __syncthreads();
        load_lds16(gA0 + k0,           lds + sA * 512);
        load_lds16(gA0 + 16 * K + k0,  lds + sA * 512 + 512);
        load_lds16(gB0 + k0,           lds + 4096 + sA * 512);
        load_lds16(gB0 + 16 * K + k0,  lds + 4096 + sA * 512 + 512);
        __syncthreads();
        short8 af[4], bf8[4];
#pragma unroll
        for (int mi = 0; mi < 4; ++mi) {
            int row = wm + mi * 16 + col;
            af[mi] = *(const short8*)(lds + row * 32 + ((quad ^ swz(row)) * 8));
        }
#pragma unroll
        for (int ni = 0; ni < 4; ++ni) {
            int row = wn + ni * 16 + col;
            bf8[ni] = *(const short8*)(lds + 4096 + row * 32 + ((quad ^ swz(row)) * 8));
        }
#pragma unroll
        for (int mi = 0; mi < 4; ++mi)
#pragma unroll
            for (int ni = 0; ni < 4; ++ni)
                acc[mi][ni] = __builtin_amdgcn_mfma_f32_16x16x32_bf16(af[mi], bf8[ni], acc[mi][ni], 0, 0, 0);
    }

    const bool lora = (MODE == 1) && (z != 1);
    // Q scale: 1/sqrt(64) * log2(e)  (attention softmax runs in exp2 domain)
    const float scale = (MODE == 1 && z == 0) ? 0.18033688011112042f : 1.0f;
    unsigned short* Ob = (MODE == 1) ? (z == 0 ? Oq : (z == 1 ? Ok : Ov)) : (unsigned short*)0;
    const float* lB = (z == 2) ? vB : qB;
    const int xoff = (z == 2) ? 8 : 0;

    float wb[4][8];
    if (lora) {
#pragma unroll
        for (int ni = 0; ni < 4; ++ni) {
            int n = tileN + wn + ni * 16 + col;
            const float4* p = (const float4*)(lB + n * 8);
            float4 w0v = p[0], w1v = p[1];
            wb[ni][0] = w0v.x; wb[ni][1] = w0v.y; wb[ni][2] = w0v.z; wb[ni][3] = w0v.w;
            wb[ni][4] = w1v.x; wb[ni][5] = w1v.y; wb[ni][6] = w1v.z; wb[ni][7] = w1v.w;
        }
    }
#pragma unroll
    for (int mi = 0; mi < 4; ++mi) {
#pragma unroll
        for (int r = 0; r < 4; ++r) {
            int m = tileM + wm + mi * 16 + quad * 4 + r;
            float xv[8];
            if (lora) {
                const float4* p = (const float4*)(xa + m * 16 + xoff);
                float4 x0 = p[0], x1 = p[1];
                xv[0] = x0.x; xv[1] = x0.y; xv[2] = x0.z; xv[3] = x0.w;
                xv[4] = x1.x; xv[5] = x1.y; xv[6] = x1.z; xv[7] = x1.w;
            }
#pragma unroll
            for (int ni = 0; ni < 4; ++ni) {
                int n = tileN + wn + ni * 16 + col;
                float val = acc[mi][ni][r];
                if (lora) {
                    float dlt = 0.f;
#pragma unroll
                    for (int j = 0; j < 8; ++j) dlt += xv[j] * wb[ni][j];
                    val += 2.f * dlt;
                }
                val *= scale;
                if (MODE == 0) {
                    Cf[(size_t)m * DD + n] = val;
                } else {
                    int b = m >> 11, t = m & 2047, h = n >> 6, d2 = n & 63;
                    Ob[((size_t)(b * HH + h) * TT + t) * DHH + d2] = f2bf(val);
                }
            }
        }
    }
}

// ---------------- split-K causal flash attention: partial kernel ----------------
// ktile=64. chunk = 16 sub-tiles (1024 kpos). grid.x = 24 (qt,chunk pairs), grid.y = bh.
// P and V stored k-PERMUTED in LDS: storage col c' = (kpos&15)*4 + (kpos>>4).
// PV is invariant under a shared k-permutation of P-cols and V-rows.
__global__ __launch_bounds__(256, 3) void attn_part_k(
        const unsigned short* __restrict__ q,
        const unsigned short* __restrict__ k,
        const unsigned short* __restrict__ v,
        unsigned short* __restrict__ Op,
        float* __restrict__ Mp, float* __restrict__ Lp) {
    __shared__ unsigned short Ps[128 * 72];      // wave-private rows [w*32, w*32+32), stride 72 shorts
    __shared__ unsigned short Vs[2 * 64 * 72];   // double-buffered V^T: [buf][dh][c'], stride 72
    int rem = blockIdx.x, qt = 0;
    while (rem >= (qt >> 3) + 1) { rem -= (qt >> 3) + 1; ++qt; }
    const int ch = rem;
    const int bh = blockIdx.y;
    const int slot = bh * 24 + blockIdx.x;
    const unsigned short* qp = q + (size_t)bh * TT * DHH;
    const unsigned short* kp = k + (size_t)bh * TT * DHH;
    const unsigned short* vp = v + (size_t)bh * TT * DHH;
    const int tid = threadIdx.x, w = tid >> 6, lane = tid & 63;
    const int col = lane & 15, quad = lane >> 4;

    short8 aq[2][2];
#pragma unroll
    for (int mt = 0; mt < 2; ++mt) {
        int t = qt * 128 + w * 32 + mt * 16 + col;
#pragma unroll
        for (int ks = 0; ks < 2; ++ks)
            aq[mt][ks] = *(const short8*)(qp + (size_t)t * DHH + ks * 32 + quad * 8);
    }
    unsigned short onev = (col == 0) ? (unsigned short)0x3F80 : (unsigned short)0;
    short8 bones;
#pragma unroll
    for (int j = 0; j < 8; ++j) bones[j] = (short)onev;

    float mrun[2][4];
    floatx4 oacc[2][4], oaccL[2];
#pragma unroll
    for (int mt = 0; mt < 2; ++mt) {
#pragma unroll
        for (int r = 0; r < 4; ++r) mrun[mt][r] = -1e30f;
#pragma unroll
        for (int nt = 0; nt < 4; ++nt) oacc[mt][nt] = (floatx4){0.f, 0.f, 0.f, 0.f};
        oaccL[mt] = (floatx4){0.f, 0.f, 0.f, 0.f};
    }

    const int sub0 = ch * 16;
    const int subN = 2 * qt + 1;
    const int sub1 = (sub0 + 15 < subN) ? sub0 + 15 : subN;

    // V staging: thread handles kpos base a (rows a, a+16, a+32, a+48), dh cols vc0..vc0+3
    const int va = tid & 15, vc0 = (tid >> 4) * 4;
    auto stageV = [&](int st, int b) {
        const unsigned short* vt = vp + (size_t)st * 64 * DHH;
        uint2 rw[4];
#pragma unroll
        for (int n = 0; n < 4; ++n)
            rw[n] = *(const uint2*)(vt + (va + 16 * n) * DHH + vc0);
        unsigned short* vsb = Vs + b * 64 * 72;
#pragma unroll
        for (int j = 0; j < 4; ++j) {
            unsigned int sel = (j & 1) ? 0x07060302u : 0x05040100u;
            unsigned int s0 = (j < 2) ? rw[0].x : rw[0].y;
            unsigned int s1 = (j < 2) ? rw[1].x : rw[1].y;
            unsigned int s2 = (j < 2) ? rw[2].x : rw[2].y;
            unsigned int s3 = (j < 2) ? rw[3].x : rw[3].y;
            uint2 o;
            o.x = __builtin_amdgcn_perm(s1, s0, sel);
            o.y = __builtin_amdgcn_perm(s3, s2, sel);
            *(uint2*)(vsb + (vc0 + j) * 72 + 4 * va) = o;  // Vs[dh][c'=4a..4a+3]
        }
    };

    stageV(sub0, 0);
    for (int st = sub0; st <= sub1; ++st) {
        const int buf = (st - sub0) & 1;
        __syncthreads();  // Vs[buf] written (prev iter prefetch / preloop) & prior reads of buf^1 done
        if (st < sub1) stageV(st + 1, buf ^ 1);
        const unsigned short* vsb = Vs + buf * 64 * 72;

        // S = Q K^T  (S in log2 domain: Q pre-scaled by 1/8 * log2 e)
        floatx4 sacc[2][4];
#pragma unroll
        for (int nt = 0; nt < 4; ++nt) {
            int kr = st * 64 + nt * 16 + col;
            short8 bk0 = *(const short8*)(kp + (size_t)kr * DHH + quad * 8);
            short8 bk1 = *(const short8*)(kp + (size_t)kr * DHH + 32 + quad * 8);
#pragma unroll
            for (int mt = 0; mt < 2; ++mt) {
                floatx4 t4 = (floatx4){0.f, 0.f, 0.f, 0.f};
                t4 = __builtin_amdgcn_mfma_f32_16x16x32_bf16(aq[mt][0], bk0, t4, 0, 0, 0);
                t4 = __builtin_amdgcn_mfma_f32_16x16x32_bf16(aq[mt][1], bk1, t4, 0, 0, 0);
                sacc[mt][nt] = t4;
            }
        }
        if (st >= 2 * qt) {  // sub-tile overlaps the causal diagonal
#pragma unroll
            for (int mt = 0; mt < 2; ++mt)
#pragma unroll
                for (int nt = 0; nt < 4; ++nt)
#pragma unroll
                    for (int r = 0; r < 4; ++r) {
                        int qpos = qt * 128 + w * 32 + mt * 16 + quad * 4 + r;
                        int kpos = st * 64 + nt * 16 + col;
                        if (kpos > qpos) sacc[mt][nt][r] = -1e30f;
                    }
        }
        // online softmax (exp2 domain), DPP row-max
        float alpha[2][4];
#pragma unroll
        for (int mt = 0; mt < 2; ++mt)
#pragma unroll
            for (int r = 0; r < 4; ++r) {
                float mx = fmaxf(fmaxf(sacc[mt][0][r], sacc[mt][1][r]),
                                 fmaxf(sacc[mt][2][r], sacc[mt][3][r]));
                mx = rowmax16(mx);
                float mnew = fmaxf(mrun[mt][r], mx);
                alpha[mt][r] = exp2f(mrun[mt][r] - mnew);
                mrun[mt][r] = mnew;
            }
        // P = exp2(S - m), pair-packed, one b64 store per (mt,r)
#pragma unroll
        for (int mt = 0; mt < 2; ++mt)
#pragma unroll
            for (int r = 0; r < 4; ++r) {
                float e0 = exp2f(sacc[mt][0][r] - mrun[mt][r]);
                float e1 = exp2f(sacc[mt][1][r] - mrun[mt][r]);
                float e2 = exp2f(sacc[mt][2][r] - mrun[mt][r]);
                float e3 = exp2f(sacc[mt][3][r] - mrun[mt][r]);
                uint2 pk;
                pk.x = pack_bf16(e0, e1);
                pk.y = pack_bf16(e2, e3);
                *(uint2*)(Ps + (w * 32 + mt * 16 + quad * 4 + r) * 72 + col * 4) = pk;
            }
#pragma unroll
        for (int mt = 0; mt < 2; ++mt) {
#pragma unroll
            for (int nt = 0; nt < 4; ++nt)
#pragma unroll
                for (int r = 0; r < 4; ++r) oacc[mt][nt][r] *= alpha[mt][r];
#pragma unroll
            for (int r = 0; r < 4; ++r) oaccL[mt][r] *= alpha[mt][r];
        }
        // O += P V ; L += P 1   (wave-private Ps: no barrier needed)
#pragma unroll
        for (int ks = 0; ks < 2; ++ks) {
            short8 ap[2], bv[4];
#pragma unroll
            for (int mt = 0; mt < 2; ++mt)
                ap[mt] = *(const short8*)(Ps + (w * 32 + mt * 16 + col) * 72 + ks * 32 + quad * 8);
#pragma unroll
            for (int nt = 0; nt < 4; ++nt)
                bv[nt] = *(const short8*)(vsb + (nt * 16 + col) * 72 + ks * 32 + quad * 8);
#pragma unroll
            for (int mt = 0; mt < 2; ++mt) {
#pragma unroll
                for (int nt = 0; nt < 4; ++nt)
                    oacc[mt][nt] = __builtin_amdgcn_mfma_f32_16x16x32_bf16(ap[mt], bv[nt], oacc[mt][nt], 0, 0, 0);
                oaccL[mt] = __builtin_amdgcn_mfma_f32_16x16x32_bf16(ap[mt], bones, oaccL[mt], 0, 0, 0);
            }
        }
    }
    // write partials: O unnormalized (bf16), m (log2 domain) and l (col-0 lanes)
    unsigned short* ob = Op + (size_t)slot * 128 * 64;
#pragma unroll
    for (int mt = 0; mt < 2; ++mt)
#pragma unroll
        for (int nt = 0; nt < 4; ++nt)
#pragma unroll
            for (int r = 0; r < 4; ++r) {
                int row = w * 32 + mt * 16 + quad * 4 + r;
                ob[row * 64 + nt * 16 + col] = f2bf(oacc[mt][nt][r]);
            }
    if (col == 0) {
#pragma unroll
        for (int mt = 0; mt < 2; ++mt)
#pragma unroll
            for (int r = 0; r < 4; ++r) {
                int row = w * 32 + mt * 16 + quad * 4 + r;
                Mp[slot * 128 + row] = mrun[mt][r];
                Lp[slot * 128 + row] = oaccL[mt][r];
            }
    }
}

// ---------------- split-K combine: O = sum_c w_c O_c / sum_c w_c l_c ----------------
__global__ __launch_bounds__(256) void attn_comb_k(
        const unsigned short* __restrict__ Op, const float* __restrict__ Mp,
        const float* __restrict__ Lp, unsigned short* __restrict__ o) {
    const int qt = blockIdx.x, bh = blockIdx.y;
    const int g = qt >> 3, nc = g + 1;
    const int slot0 = bh * 24 + 4 * g * (g + 1) + (qt & 7) * (g + 1);
    const int b = bh >> 4, h = bh & 15;
    const int tid = threadIdx.x;
    const int row = tid >> 1, d0 = (tid & 1) * 32;
    float m0 = Mp[slot0 * 128 + row];
    float m1 = (nc > 1) ? Mp[(slot0 + 1) * 128 + row] : -1e30f;
    float M = fmaxf(m0, m1);
    float w0 = exp2f(m0 - M);
    float w1 = (nc > 1) ? exp2f(m1 - M) : 0.f;
    float ltot = w0 * Lp[slot0 * 128 + row];
    if (nc > 1) ltot += w1 * Lp[(slot0 + 1) * 128 + row];
    float inv = 1.0f / ltot;
    const unsigned short* p0 = Op + (size_t)slot0 * 8192 + row * 64 + d0;
    float acc[32];
#pragma unroll
    for (int c4 = 0; c4 < 4; ++c4) {
        short8 vv = *(const short8*)(p0 + c4 * 8);
#pragma unroll
        for (int j = 0; j < 8; ++j) acc[c4 * 8 + j] = w0 * bf2f((unsigned short)vv[j]);
    }
    if (nc > 1) {
        const unsigned short* p1 = p0 + 8192;
#pragma unroll
        for (int c4 = 0; c4 < 4; ++c4) {
            short8 vv = *(const short8*)(p1 + c4 * 8);
#pragma unroll
            for (int j = 0; j < 8; ++j) acc[c4 * 8 + j] += w1 * bf2f((unsigned short)vv[j]);
        }
    }
    unsigned short* po = o + ((size_t)(b * TT + qt * 128 + row)) * DD + h * DHH + d0;
#pragma unroll
    for (int c4 = 0; c4 < 4; ++c4) {
        short8 ov;
#pragma unroll
        for (int j = 0; j < 8; ++j) ov[j] = (short)f2bf(acc[c4 * 8 + j] * inv);
        *(short8*)(po + c4 * 8) = ov;
    }
}

extern "C" void kernel_launch(void* const* d_in, const int* in_sizes, int n_in,
                              void* d_out, int out_size, void* d_ws, size_t ws_size,
                              hipStream_t stream) {
    const float* x    = (const float*)d_in[0];
    const float* wq_w = (const float*)d_in[2];
    const float* wq_A = (const float*)d_in[3];
    const float* wq_B = (const float*)d_in[4];
    const float* wk_w = (const float*)d_in[5];
    const float* wv_w = (const float*)d_in[6];
    const float* wv_A = (const float*)d_in[7];
    const float* wv_B = (const float*)d_in[8];
    const float* wo_w = (const float*)d_in[9];
    float* out = (float*)d_out;

    char* ws = (char*)d_ws;
    unsigned short* xb  = (unsigned short*)(ws + 0);         // 8 MB   [dead after QKV gemm]
    unsigned short* wqb = (unsigned short*)(ws + 8388608);   // 2 MB   [dead after QKV gemm]
    unsigned short* wkb = (unsigned short*)(ws + 10485760);  //        [dead after QKV gemm]
    unsigned short* wvb = (unsigned short*)(ws + 12582912);  //        [dead after QKV gemm]
    unsigned short* wob = (unsigned short*)(ws + 14680064);  // 2 MB   [live until final gemm]
    float*          xa  = (float*)         (ws + 16777216);  // 256 KB
    unsigned short* qb  = (unsigned short*)(ws + 17039360);  // 8 MB each, [b,h,t,dh]
    unsigned short* kb  = (unsigned short*)(ws + 25427968);
    unsigned short* vb  = (unsigned short*)(ws + 33816576);
    unsigned short* ob  = (unsigned short*)(ws + 42205184);  // 8 MB, [b,t,h*dh]
    // split-K partials overlay the dead xb/wqb/wkb/wvb region (stream-ordered safe):
    unsigned short* Opart = (unsigned short*)(ws + 0);         // 32*24*8192*2 = 12,582,912 B
    float*          Mpart = (float*)         (ws + 12582912);  // 393,216 B
    float*          Lpart = (float*)         (ws + 12976128);  // 393,216 B  (ends < wob)

    cast_all_k<<<8192, 256, 0, stream>>>(x, wq_w, wk_w, wv_w, wo_w, xb, wqb, wkb, wvb, wob);
    lora_xa_k<<<1024, 256, 0, stream>>>(x, wq_A, wv_A, xa);
    gemm_nt_k<1><<<dim3(8, 32, 3), 256, 0, stream>>>(xb, wqb, wkb, wvb, qb, kb, vb,
                                                     nullptr, xa, wq_B, wv_B);
    attn_part_k<<<dim3(24, 32), 256, 0, stream>>>(qb, kb, vb, Opart, Mpart, Lpart);
    attn_comb_k<<<dim3(16, 32), 256, 0, stream>>>(Opart, Mpart, Lpart, ob);
    gemm_nt_k<0><<<dim3(8, 32, 1), 256, 0, stream>>>(ob, wob, nullptr, nullptr,
                                                     nullptr, nullptr, nullptr, out,
                                                     nullptr, nullptr, nullptr);
}